// Round 2
// baseline (124.179 us; speedup 1.0000x reference)
//
#include <hip/hip_runtime.h>
#include <hip/hip_bf16.h>

// AdaptiveGraphNetwork via MFMA 16x16x32 bf16. B=4096, N=64, D=32, H=64.
// One WG processes NBATCH=8 batches (NBI=2 per iteration); weight fragments
// loaded ONCE per WG into registers (A-frag of W^T == B-frag of W, so the
// same fragments serve both orientations).
//
// v2 changes vs 121.4us baseline:
//  * Phases A/B/C compute the TRANSPOSED product (swapped MFMA operands:
//    h^T = Wm1^T @ x^T etc). The C-fragment then holds 4 values contiguous
//    along the feature dim of one LDS row -> packed ds_write_b64 stores
//    (was 128 scalar ds_write_u16 per wave-iter, now 32 b64).
//  * A->B and C->D are wave-local (producer rows == consumer rows per wave):
//    the two interior __syncthreads() become wave-level lgkmcnt fences.
//  * Remaining 2 barriers are lgkmcnt-only s_barrier (no vmcnt drain; there
//    are no cross-wave dependencies through global memory).
//
// Fragment maps (m89/m91-verified): A[m=lane&15][k=quad*8+j],
// B[k=quad*8+j][n=lane&15], C/D[row=quad*4+reg][col=lane&15].

typedef __bf16 bf16x8 __attribute__((ext_vector_type(8)));
typedef float  f32x4  __attribute__((ext_vector_type(4)));
typedef unsigned short u16;

#define NBATCH 8
#define NBI 2
#define ITERS (NBATCH / NBI)
#define HS  72   // sH row stride in u16 (144 B, 16B-aligned)
#define MBS 40   // sMB row stride in u16 (80 B, 16B-aligned)

__device__ __forceinline__ u16 f2b(float f) { return __builtin_bit_cast(u16, (__bf16)f); }
__device__ __forceinline__ f32x4 MFMA(bf16x8 a, bf16x8 b, f32x4 c) {
    return __builtin_amdgcn_mfma_f32_16x16x32_bf16(a, b, c, 0, 0, 0);
}
__device__ __forceinline__ bf16x8 pack8(float4 a, float4 b) {
    bf16x8 r = {(__bf16)a.x, (__bf16)a.y, (__bf16)a.z, (__bf16)a.w,
                (__bf16)b.x, (__bf16)b.y, (__bf16)b.z, (__bf16)b.w};
    return r;
}
// relu(acc + bias) for the 4 C^T rows of one lane, packed as 4 bf16.
__device__ __forceinline__ uint2 relu_pack4(f32x4 acc, f32x4 bias) {
    uint2 o;
    o.x = (unsigned)f2b(fmaxf(acc[0] + bias[0], 0.f)) |
          ((unsigned)f2b(fmaxf(acc[1] + bias[1], 0.f)) << 16);
    o.y = (unsigned)f2b(fmaxf(acc[2] + bias[2], 0.f)) |
          ((unsigned)f2b(fmaxf(acc[3] + bias[3], 0.f)) << 16);
    return o;
}
// Wave-local LDS producer->consumer fence: ds_writes by this wave's lanes are
// visible to this wave's ds_reads after lgkmcnt(0) (same-wave LDS is in-order
// through the pipe; no s_barrier needed). "memory" clobber pins code motion.
__device__ __forceinline__ void wave_lds_fence() {
    asm volatile("s_waitcnt lgkmcnt(0)" ::: "memory");
}
// Cross-wave barrier that drains LDS only (no vmcnt: no cross-wave global deps).
__device__ __forceinline__ void barrier_lds() {
    asm volatile("s_waitcnt lgkmcnt(0)" ::: "memory");
    __builtin_amdgcn_s_barrier();
    asm volatile("" ::: "memory");
}

__global__ __launch_bounds__(256, 2)
void agn_mfma(const float* __restrict__ x, const float* __restrict__ Wm1,
              const float* __restrict__ bm1, const float* __restrict__ Wm2,
              const float* __restrict__ bm2, const float* __restrict__ Wu1,
              const float* __restrict__ bu1, const float* __restrict__ Wu2,
              const float* __restrict__ bu2, const float* __restrict__ rw_p,
              float* __restrict__ out)
{
    __shared__ __align__(16) u16 sH[256 * HS];    // rows 0..255 edge-h; rows 0..127 reused as hu
    __shared__ __align__(16) u16 sMB[256 * MBS];

    const int t = threadIdx.x;
    const int w = t >> 6;
    const int lane = t & 63;
    const int ln = lane & 15;
    const int q  = lane >> 4;

    // ---------------- weight fragments (once per WG) ----------------
    // A-frag of W^T == B-frag of W: these loads serve the swapped phases as-is.
    bf16x8 B1a[4], B1b[4], B2[2][2], B3[2][4], B4[2][2];
#pragma unroll
    for (int nt = 0; nt < 4; ++nt)
#pragma unroll
        for (int j = 0; j < 8; ++j) {
            B1a[nt][j] = (__bf16)Wm1[(q * 8 + j) * 64 + nt * 16 + ln];
            B1b[nt][j] = (__bf16)Wm1[(32 + q * 8 + j) * 64 + nt * 16 + ln];
        }
#pragma unroll
    for (int s = 0; s < 2; ++s)
#pragma unroll
        for (int nt = 0; nt < 2; ++nt)
#pragma unroll
            for (int j = 0; j < 8; ++j)
                B2[s][nt][j] = (__bf16)Wm2[(s * 32 + q * 8 + j) * 32 + nt * 16 + ln];
#pragma unroll
    for (int s = 0; s < 2; ++s)
#pragma unroll
        for (int nt = 0; nt < 4; ++nt)
#pragma unroll
            for (int j = 0; j < 8; ++j)
                B3[s][nt][j] = (__bf16)Wu1[(s * 32 + q * 8 + j) * 64 + nt * 16 + ln];
#pragma unroll
    for (int s = 0; s < 2; ++s)
#pragma unroll
        for (int nt = 0; nt < 2; ++nt)
#pragma unroll
            for (int j = 0; j < 8; ++j)
                B4[s][nt][j] = (__bf16)Wu2[(s * 32 + q * 8 + j) * 32 + nt * 16 + ln];

    // Biases. Swapped phases (A/B/C) index by C^T row = tile*16 + q*4 + r.
    f32x4 bm1s[4], bu1s[4], bm2s[2];
#pragma unroll
    for (int ht = 0; ht < 4; ++ht)
#pragma unroll
        for (int r = 0; r < 4; ++r) {
            bm1s[ht][r] = bm1[ht * 16 + q * 4 + r];
            bu1s[ht][r] = bu1[ht * 16 + q * 4 + r];
        }
#pragma unroll
    for (int s = 0; s < 2; ++s)
#pragma unroll
        for (int r = 0; r < 4; ++r)
            bm2s[s][r] = bm2[s * 16 + q * 4 + r];
    float bu2v[2];
#pragma unroll
    for (int nt = 0; nt < 2; ++nt) bu2v[nt] = bu2[nt * 16 + ln];
    const float rw = rw_p[0];
    const float om = 1.f - rw;

    const size_t base = (size_t)blockIdx.x * (NBATCH * 64 * 32);

    for (int it = 0; it < ITERS; ++it) {
        const float* xit = x + base + (size_t)it * (NBI * 64 * 32);
        float*       oit = out + base + (size_t)it * (NBI * 64 * 32);

        // ===== Phase A (swapped): h^T = Wm1t^T@xd^T + Wm1b^T@xs^T, relu =====
        // C^T[hf=ht*16+q*4+r][edge=et*16+ln] -> packed b64 to sH[edge][hf].
        {
            float4 xd[4][2], xsv[4][2];
#pragma unroll
            for (int m = 0; m < 4; ++m) {
                const int et = 4 * w + m;
                const int erow = et * 16 + ln;
                const int bb = erow >> 7;
                int e = erow & 127;
                if (e >= 126) e = 0;  // pad rows, never read downstream
                const int dst  = (e < 63) ? e : e - 62;
                const int srcn = (e < 63) ? e + 1 : e - 63;
                const float* pd = xit + ((bb << 6) + dst) * 32 + q * 8;
                const float* ps = xit + ((bb << 6) + srcn) * 32 + q * 8;
                xd[m][0] = *(const float4*)pd;  xd[m][1] = *(const float4*)(pd + 4);
                xsv[m][0] = *(const float4*)ps; xsv[m][1] = *(const float4*)(ps + 4);
            }
#pragma unroll
            for (int m = 0; m < 4; ++m) {
                const int erow = (4 * w + m) * 16 + ln;
                bf16x8 Ad = pack8(xd[m][0], xd[m][1]);
                bf16x8 As = pack8(xsv[m][0], xsv[m][1]);
                u16* rowp = &sH[erow * HS];
#pragma unroll
                for (int ht = 0; ht < 4; ++ht) {
                    f32x4 acc = {0.f, 0.f, 0.f, 0.f};
                    acc = MFMA(B1a[ht], Ad, acc);   // swapped: W-frag as A, x-frag as B
                    acc = MFMA(B1b[ht], As, acc);
                    *(uint2*)&rowp[ht * 16 + q * 4] = relu_pack4(acc, bm1s[ht]);
                }
            }
        }
        wave_lds_fence();  // A->B is wave-local (rows [64w,64w+64))

        // ===== Phase B (swapped): msgb^T = Wm2^T @ h^T, relu =====
#pragma unroll
        for (int m = 0; m < 4; ++m) {
            const int row = (4 * w + m) * 16 + ln;
            bf16x8 A0 = __builtin_bit_cast(bf16x8, *(const uint4*)&sH[row * HS + q * 8]);
            bf16x8 A1 = __builtin_bit_cast(bf16x8, *(const uint4*)&sH[row * HS + 32 + q * 8]);
#pragma unroll
            for (int s = 0; s < 2; ++s) {
                f32x4 acc = {0.f, 0.f, 0.f, 0.f};
                acc = MFMA(B2[0][s], A0, acc);
                acc = MFMA(B2[1][s], A1, acc);
                *(uint2*)&sMB[row * MBS + s * 16 + q * 4] = relu_pack4(acc, bm2s[s]);
            }
        }
        barrier_lds();  // sMB scatter in C is cross-wave

        // ===== Phase C (swapped): hu^T = Wu1^T @ [x | scatter(msgb)]^T, relu =====
#pragma unroll
        for (int m = 0; m < 2; ++m) {
            const int row = (2 * w + m) * 16 + ln;   // node row in 2-batch chunk
            const int bb = row >> 6;
            const int i2 = row & 63;
            const float* p = xit + row * 32 + q * 8;
            float4 a0 = *(const float4*)p;
            float4 a1 = *(const float4*)(p + 4);
            bf16x8 A0 = pack8(a0, a1);
            float mv[8] = {0.f, 0.f, 0.f, 0.f, 0.f, 0.f, 0.f, 0.f};
            if (i2 < 63) {
                uint4 u = *(const uint4*)&sMB[((bb << 7) + i2) * MBS + q * 8];
                const unsigned* pu = (const unsigned*)&u;
#pragma unroll
                for (int h = 0; h < 4; ++h) {
                    mv[2 * h]     += __uint_as_float(pu[h] << 16);
                    mv[2 * h + 1] += __uint_as_float(pu[h] & 0xFFFF0000u);
                }
            }
            if (i2 > 0) {
                uint4 u = *(const uint4*)&sMB[((bb << 7) + 62 + i2) * MBS + q * 8];
                const unsigned* pu = (const unsigned*)&u;
#pragma unroll
                for (int h = 0; h < 4; ++h) {
                    mv[2 * h]     += __uint_as_float(pu[h] << 16);
                    mv[2 * h + 1] += __uint_as_float(pu[h] & 0xFFFF0000u);
                }
            }
            bf16x8 A1;
#pragma unroll
            for (int j = 0; j < 8; ++j) A1[j] = (__bf16)mv[j];
#pragma unroll
            for (int ht = 0; ht < 4; ++ht) {
                f32x4 acc = {0.f, 0.f, 0.f, 0.f};
                acc = MFMA(B3[0][ht], A0, acc);
                acc = MFMA(B3[1][ht], A1, acc);
                *(uint2*)&sH[row * HS + ht * 16 + q * 4] = relu_pack4(acc, bu1s[ht]);
            }
        }
        wave_lds_fence();  // C->D is wave-local (rows [32w,32w+32))

        // ===== Phase D (normal): out = rw*(hu @ Wu2 + bu2) + (1-rw)*x =====
#pragma unroll
        for (int m = 0; m < 2; ++m) {
            const int mt = 2 * w + m;
            const int arow = mt * 16 + ln;
            bf16x8 A0 = __builtin_bit_cast(bf16x8, *(const uint4*)&sH[arow * HS + q * 8]);
            bf16x8 A1 = __builtin_bit_cast(bf16x8, *(const uint4*)&sH[arow * HS + 32 + q * 8]);
#pragma unroll
            for (int nt = 0; nt < 2; ++nt) {
                f32x4 acc = {0.f, 0.f, 0.f, 0.f};
                acc = MFMA(A0, B4[0][nt], acc);
                acc = MFMA(A1, B4[1][nt], acc);
                const int rb = mt * 16 + q * 4;
                const int c  = nt * 16 + ln;
#pragma unroll
                for (int r = 0; r < 4; ++r) {
                    const int off = (rb + r) * 32 + c;
                    oit[off] = rw * (acc[r] + bu2v[nt]) + om * xit[off];
                }
            }
        }
        barrier_lds();  // sH (=hu) consumed before next iter's Phase A overwrites
    }
}

extern "C" void kernel_launch(void* const* d_in, const int* in_sizes, int n_in,
                              void* d_out, int out_size, void* d_ws, size_t ws_size,
                              hipStream_t stream) {
    const float* x   = (const float*)d_in[0];
    const float* Wm1 = (const float*)d_in[1];
    const float* bm1 = (const float*)d_in[2];
    const float* Wm2 = (const float*)d_in[3];
    const float* bm2 = (const float*)d_in[4];
    const float* Wu1 = (const float*)d_in[5];
    const float* bu1 = (const float*)d_in[6];
    const float* Wu2 = (const float*)d_in[7];
    const float* bu2 = (const float*)d_in[8];
    const float* rw  = (const float*)d_in[9];
    float* out = (float*)d_out;

    const int B = in_sizes[0] / (64 * 32);
    agn_mfma<<<B / NBATCH, 256, 0, stream>>>(x, Wm1, bm1, Wm2, bm2, Wu1, bu1, Wu2, bu2, rw, out);
}